// Round 19
// baseline (289.542 us; speedup 1.0000x reference)
//
#include <hip/hip_runtime.h>
#include <hip/hip_bf16.h>

typedef __bf16 bf16_t;
typedef __attribute__((ext_vector_type(8))) __bf16 bf16x8;
typedef __attribute__((ext_vector_type(4))) __bf16 bf16x4;
typedef __attribute__((ext_vector_type(4))) float f32x4;

#define GLD16(gp, lp) __builtin_amdgcn_global_load_lds( \
    (__attribute__((address_space(1))) void*)(gp), \
    (__attribute__((address_space(3))) void*)(lp), 16, 0, 0)

static constexpr int Bn = 4, Hc = 128, Wc = 128, Cc = 256;
static constexpr int Tt = Hc * Wc;          // 16384
static constexpr int Mrows = Bn * Tt;       // 65536
static constexpr int NC = 256, CL = 64;     // wkv chunks: 256 chunks of 64
                                            // [R14 lesson: CL=32 cost +18us]
// [R17/R18 lesson: proj@TM=128 failure was a GRID bug (copied kvr's nbx=6 for
//  an N=256 output -> OOB epilogue writes corrupted xcat), NOT the fan-in
//  fusion per se. Grid is part of the tile contract.]

// bijective XCD-aware swizzle (m204): contiguous work chunk per XCD
__device__ inline int xcd_swizzle(int orig, int nb)
{
    int q = nb >> 3, r = nb & 7;
    int xcd = orig & 7, slot = orig >> 3;
    return (xcd < r ? xcd * (q + 1) : r * (q + 1) + (xcd - r) * q) + slot;
}

// --- prep: cast x -> xcat; fold mixes, concat, cast weights; dw transpose ---
// blocks [0,8192): cast x;  [8192,11008): weight prep;  [11008,11035): dw^T
__global__ void prep_all(const float* __restrict__ x, bf16_t* __restrict__ xcat,
                         const float* __restrict__ c1,
                         const float* __restrict__ p1, const float* __restrict__ p2,
                         const float* __restrict__ p3,
                         const float* __restrict__ kw, const float* __restrict__ vw,
                         const float* __restrict__ rw, const float* __restrict__ ow,
                         const float* __restrict__ mk, const float* __restrict__ mv,
                         const float* __restrict__ mr,
                         const float* __restrict__ w1, const float* __restrict__ w2,
                         const float* __restrict__ w3,
                         bf16_t* __restrict__ wbf, bf16_t* __restrict__ dwtb)
{
    int bx = blockIdx.x;
    if (bx < 8192) {                          // cast x (8 f32/thread)
        int i = bx * 256 + threadIdx.x;
        int p = i >> 5;
        int cc = (i & 31) * 8;
        const float4* s = (const float4*)(x + (size_t)p * 256 + cc);
        float4 a = s[0], b = s[1];
        bf16x8 o;
        o[0] = (bf16_t)a.x; o[1] = (bf16_t)a.y; o[2] = (bf16_t)a.z; o[3] = (bf16_t)a.w;
        o[4] = (bf16_t)b.x; o[5] = (bf16_t)b.y; o[6] = (bf16_t)b.z; o[7] = (bf16_t)b.w;
        *(bf16x8*)(xcat + (size_t)p * 512 + cc) = o;
        return;
    }
    bx -= 8192;
    if (bx >= 2816) {                         // dw weight transpose tail (bf16)
        int tap = bx - 2816;                  // 0..26
        int c   = threadIdx.x;
        const float* src = (tap < 9) ? w1 : (tap < 18) ? w2 : w3;
        dwtb[tap * 256 + c] = (bf16_t)src[c * 9 + (tap % 9)];
        return;
    }
    int i = bx * 256 + threadIdx.x;           // 0 .. 720895
    float v;
    if (i < 65536) {                          // conv1 [256][256]
        v = c1[i];
    } else if (i < 262144) {                  // projcat [256][768]
        int j = i - 65536;
        int n = j / 768, k = j % 768;
        int br = k >> 8, c = k & 255;
        const float* pw = (br == 0) ? p1 : (br == 1) ? p2 : p3;
        v = pw[n * 256 + c];
    } else if (i < 655360) {                  // kvrcat [768][512], mix folded
        int j = i - 262144;
        int n = j / 512, k = j % 512;
        const float* W; const float* mix;
        if (n < 256)      { W = kw; mix = mk; }
        else if (n < 512) { W = vw; mix = mv; }
        else              { W = rw; mix = mr; }
        int nn = n & 255, c = k & 255;
        float m = mix[c];
        float f = (k < 256) ? m : (1.0f - m);
        v = W[nn * 256 + c] * f;
    } else {                                  // out_w [256][256]
        v = ow[i - 655360];
    }
    wbf[i] = (bf16_t)v;
}

// ---------------- bf16 MFMA GEMM, C = A @ Bw^T  (Bw is [N][K]) --------------
// Tile-M templated, per-GEMM selection (measured):
//   TM=128: 4 waves, 32 KiB LDS, 4 blocks/CU -> best for long-K (kvr: 71us)
//   TM=256: 8 waves, 48 KiB LDS, 3 blocks/CU -> best for short-K (conv1/out)
// Per K-tile: STAGE -> sync -> ds_read frags + 32 MFMA/wave -> sync; barrier
// drain hidden by co-resident blocks (m114 overlap).
// T2 swizzle: LDS block b of row r holds global block b^(r&7); GLD16 keeps a
// linear LDS dest, the global SOURCE is inverse-permuted, ds_read XORs back.
// EPI 0: store bf16                EPI 1: store bf16(aux + acc)  (xx = x + s)
// EPI 2: split store k/v/r (block-uniform), sigmoid on r      EPI 3: store f32
template<int EPI, int TM>
__global__ __launch_bounds__(TM * 2, 4)
void gemm_bt(const bf16_t* __restrict__ A, int lda,
             const bf16_t* __restrict__ Bw, int K,
             bf16_t* __restrict__ Cb, bf16_t* __restrict__ Cb2,
             bf16_t* __restrict__ Cb3,
             float* __restrict__ Cf, int ldc,
             const bf16_t* __restrict__ aux, int aux_ld)
{
    constexpr int RA = TM / 4;           // rows per staged chunk
    constexpr int CB = 512 / TM;         // B chunks (128 rows total)
    __shared__ bf16_t sA[TM * 64];
    __shared__ bf16_t sB[128 * 64];
    const int tid  = threadIdx.x;
    const int wid  = tid >> 6, lane = tid & 63;
    const int nbx  = gridDim.x;
    int work = xcd_swizzle(blockIdx.y * nbx + blockIdx.x, nbx * gridDim.y);
    const int bcol = (work % nbx) * 128;
    const int brow = (work / nbx) * TM;
    const int wm = (wid >> 1) * 64, wn = (wid & 1) * 64;   // wave tile 64x64
    const int lr = lane & 15, lq = lane >> 4;
    const int r0 = tid >> 3;             // staging row within chunk
    const int l7 = tid & 7;              // staging 16B-block within row
    const int sblk = l7 ^ (r0 & 7);      // inverse-swizzled source block

    f32x4 acc[4][4] = {};

    // stage one K-tile: A TM x 64 (4 chunks), B 128 x 64 (CB chunks);
    // linear LDS dest (wave-uniform base + lane*16), pre-swizzled source.
    auto STAGE = [&](int k0) {
#pragma unroll
        for (int c = 0; c < 4; c++)
            GLD16(A + (size_t)(brow + c * RA + r0) * lda + k0 + sblk * 8,
                  &sA[(c * RA + wid * 8) * 64]);
#pragma unroll
        for (int c = 0; c < CB; c++)
            GLD16(Bw + (size_t)(bcol + c * RA + r0) * K + k0 + sblk * 8,
                  &sB[(c * RA + wid * 8) * 64]);
    };

    const int knt = K >> 6;
    for (int t = 0; t < knt; ++t) {
        STAGE(t * 64);
        __syncthreads();                 // drain stage; other blocks hide it
        bf16x8 af[2][4], bg[2][4];
#pragma unroll
        for (int kk = 0; kk < 2; kk++) {
#pragma unroll
            for (int m = 0; m < 4; m++) {
                int rr = wm + m * 16 + lr;
                af[kk][m] = *(const bf16x8*)&sA
                    [rr * 64 + (((kk << 2) | lq) ^ (rr & 7)) * 8];
            }
#pragma unroll
            for (int n = 0; n < 4; n++) {
                int rr = wn + n * 16 + lr;
                bg[kk][n] = *(const bf16x8*)&sB
                    [rr * 64 + (((kk << 2) | lq) ^ (rr & 7)) * 8];
            }
        }
#pragma unroll
        for (int kk = 0; kk < 2; kk++)
#pragma unroll
            for (int m = 0; m < 4; m++)
#pragma unroll
                for (int n = 0; n < 4; n++)
                    acc[m][n] = __builtin_amdgcn_mfma_f32_16x16x32_bf16(
                        af[kk][m], bg[kk][n], acc[m][n], 0, 0, 0);
        __syncthreads();                 // all reads done before next STAGE
    }

    // epilogue: C/D layout col = lane&15, row = (lane>>4)*4 + j
#pragma unroll
    for (int m = 0; m < 4; m++) {
#pragma unroll
        for (int n = 0; n < 4; n++) {
            int col  = bcol + wn + n * 16 + lr;
            int row0 = brow + wm + m * 16 + lq * 4;
#pragma unroll
            for (int j = 0; j < 4; j++) {
                int row = row0 + j;
                float v = acc[m][n][j];
                if constexpr (EPI == 0) {
                    Cb[(size_t)row * ldc + col] = (bf16_t)v;
                } else if constexpr (EPI == 1) {
                    float xv = (float)aux[(size_t)row * aux_ld + col];
                    Cb[(size_t)row * ldc + col] = (bf16_t)(xv + v);
                } else if constexpr (EPI == 2) {
                    int cb = bcol >> 8;                // block-uniform: 0,1,2
                    bf16_t* dst = (cb == 0) ? Cb : (cb == 1) ? Cb2 : Cb3;
                    if (cb == 2) v = 1.0f / (1.0f + __expf(-v));
                    dst[(size_t)row * 256 + (col & 255)] = (bf16_t)v;
                } else {
                    Cf[(size_t)row * ldc + col] = v;
                }
            }
        }
    }
}

// ---------------- depthwise 3x3, dilations 1/2/3 -> dcat [M][768] -----------
// 4-pixel horizontal strip per thread, 8 channels. For 4 adjacent pixels the
// tap columns per (d,kh) form ONE contiguous span w-d..w+3+d (6/8/10 cols):
// load the span once, index statically sp[p + kw2*d] (fully unrolled).
template<int D>
__device__ inline void dw_dil(const bf16_t* __restrict__ mid, size_t img,
                              int h, int w, int c0, const bf16_t* swt,
                              bf16_t* __restrict__ dcat, size_t p0)
{
    constexpr int S = 4 + 2 * D;
    float acc[4][8] = {};
    const bf16x8 z = {};
#pragma unroll
    for (int kh = 0; kh < 3; kh++) {
        int hh = h + (kh - 1) * D;
        bool okh = (unsigned)hh < 128u;
        int hc = min(max(hh, 0), 127);
        const bf16_t* rowp = mid + (img + (size_t)(hc * 128)) * 256 + c0;
        bf16x8 sp[S];
#pragma unroll
        for (int s = 0; s < S; s++) {
            int ww = w - D + s;
            bool ok = okh && ((unsigned)ww < 128u);
            int wc = min(max(ww, 0), 127);
            bf16x8 m = *(const bf16x8*)(rowp + (size_t)wc * 256);
            sp[s] = ok ? m : z;
        }
#pragma unroll
        for (int kw2 = 0; kw2 < 3; kw2++) {
            bf16x8 wv = *(const bf16x8*)&swt[((D - 1) * 9 + kh * 3 + kw2) * 256 + c0];
#pragma unroll
            for (int p = 0; p < 4; p++) {
                bf16x8 m = sp[p + kw2 * D];
#pragma unroll
                for (int j = 0; j < 8; j++)
                    acc[p][j] += (float)m[j] * (float)wv[j];
            }
        }
    }
#pragma unroll
    for (int p = 0; p < 4; p++) {
        bf16x8 o;
#pragma unroll
        for (int j = 0; j < 8; j++) o[j] = (bf16_t)acc[p][j];
        *(bf16x8*)(dcat + (size_t)(p0 + p) * 768 + (D - 1) * 256 + c0) = o;
    }
}

__global__ __launch_bounds__(256)
void dw_kernel(const bf16_t* __restrict__ mid,
               const bf16_t* __restrict__ dwtb,
               bf16_t* __restrict__ dcat)
{
    __shared__ bf16_t swt[27 * 256];
    for (int i = threadIdx.x * 8; i < 27 * 256; i += 256 * 8)
        *(bf16x8*)&swt[i] = *(const bf16x8*)(dwtb + i);
    __syncthreads();

    int blk = xcd_swizzle(blockIdx.x, gridDim.x);   // L2-local halo reuse
    size_t p0 = (size_t)blk * 32 + (threadIdx.x >> 5) * 4;  // 4-px strip
    int c0 = (threadIdx.x & 31) * 8;                // channel group
    int t  = (int)(p0 & 16383);
    int h  = t >> 7, w = t & 127;
    size_t img = (p0 >> 14) << 14;                  // image base (pixels)

    dw_dil<1>(mid, img, h, w, c0, swt, dcat, p0);
    dw_dil<2>(mid, img, h, w, c0, swt, dcat, p0);
    dw_dil<3>(mid, img, h, w, c0, swt, dcat, p0);
}

// ---------------- WKV chunked scan (CL=64, NC=256) --------------------------
// pass1: per-chunk local (a,b,p) summary from zero state (prefetch next step)
__global__ void wkv_pass1(const bf16_t* __restrict__ kb, const bf16_t* __restrict__ vb,
                          const float* __restrict__ decay,
                          float* __restrict__ A1, float* __restrict__ B1,
                          float* __restrict__ P1)
{
    int c = threadIdx.x;
    int j = blockIdx.x;            // chunk
    int b = blockIdx.y;
    float wneg = -__expf(decay[c] * (1.0f / 16384.0f));
    float aa = 0.0f, bb = 0.0f, pp = -1e38f;
    size_t base = ((size_t)b * 16384 + (size_t)j * CL) * 256 + c;
    float kk = (float)kb[base];
    float vv = (float)vb[base];
    for (int i = 0; i < CL; i++) {
        float kk2 = 0.0f, vv2 = 0.0f;
        if (i + 1 < CL) {
            kk2 = (float)kb[base + 256];
            vv2 = (float)vb[base + 256];
        }
        float ww2 = wneg + pp;
        float p2  = fmaxf(ww2, kk);
        float e1  = __expf(ww2 - p2);
        float e2  = __expf(kk - p2);
        aa = e1 * aa + e2 * vv;
        bb = e1 * bb + e2;
        pp = p2;
        kk = kk2; vv = vv2;
        base += 256;
    }
    int idx = ((b * NC + j) * 256) + c;
    A1[idx] = aa; B1[idx] = bb; P1[idx] = pp;
}

// pass2: serial combine across chunks -> chunk-entry states.
// 16 blocks x 64 threads; unroll-4 with batched loads (latency / 4).
__global__ void wkv_pass2(const float* __restrict__ decay,
                          const float* __restrict__ A1, const float* __restrict__ B1,
                          const float* __restrict__ P1,
                          float* __restrict__ A2, float* __restrict__ B2,
                          float* __restrict__ P2)
{
    int c = (blockIdx.x & 3) * 64 + threadIdx.x;   // channel 0..255
    int b = blockIdx.x >> 2;                        // batch
    float wneg = -__expf(decay[c] * (1.0f / 16384.0f));
    float Lw = (float)CL * wneg;
    float aa = 0.0f, bb = 0.0f, pp = -1e38f;
    for (int j = 0; j < NC; j += 4) {
        float a4[4], b4[4], p4[4];
#pragma unroll
        for (int u = 0; u < 4; u++) {
            int idx = ((b * NC + j + u) * 256) + c;
            a4[u] = A1[idx]; b4[u] = B1[idx]; p4[u] = P1[idx];
        }
#pragma unroll
        for (int u = 0; u < 4; u++) {
            int idx = ((b * NC + j + u) * 256) + c;
            A2[idx] = aa; B2[idx] = bb; P2[idx] = pp;
            float q  = pp + Lw;
            float pn = fmaxf(q, p4[u]);
            float e1 = __expf(q - pn);
            float e2 = __expf(p4[u] - pn);
            aa = e1 * aa + e2 * a4[u];
            bb = e1 * bb + e2 * b4[u];
            pp = pn;
        }
    }
}

// pass3: re-run chunk with correct entry state + fused LayerNorm + gate ------
// Light barrier: lgkmcnt(0) (orders lane-0's part[] ds_write) + raw s_barrier
// -- NOT __syncthreads, whose vmcnt(0) drain would kill the k/v/r prefetch.
__global__ __launch_bounds__(256)
void wkv_pass3(const bf16_t* __restrict__ kb, const bf16_t* __restrict__ vb,
               const bf16_t* __restrict__ rb,
               const float* __restrict__ decay, const float* __restrict__ first,
               const float* __restrict__ A2, const float* __restrict__ B2,
               const float* __restrict__ P2,
               const float* __restrict__ gamma, const float* __restrict__ beta,
               bf16_t* __restrict__ abf)
{
    __shared__ float part[2][2][4];    // [step&1][s|sq][wave]
    int c = threadIdx.x;
    int j = blockIdx.x;
    int b = blockIdx.y;
    int wv = c >> 6, lane = c & 63;
    float wneg = -__expf(decay[c] * (1.0f / 16384.0f));
    float u  = first[c] * (1.0f / 16384.0f);
    float gm = gamma[c], bt = beta[c];
    int idx = ((b * NC + j) * 256) + c;
    float aa = A2[idx], bb = B2[idx], pp = P2[idx];
    size_t base = ((size_t)b * 16384 + (size_t)j * CL) * 256 + c;

    float kk = (float)kb[base];
    float vv = (float)vb[base];
    float rv = (float)rb[base];
    for (int i = 0; i < CL; i++) {
        float ww = u + kk;
        float p  = fmaxf(pp, ww);
        float e1 = __expf(pp - p);
        float e2 = __expf(ww - p);
        float y  = (e1 * aa + e2 * vv) / (e1 * bb + e2);
        // prefetch next step; stays in flight across the light barrier
        float kk2 = 0.0f, vv2 = 0.0f, rv2 = 0.0f;
        if (i + 1 < CL) {
            kk2 = (float)kb[base + 256];
            vv2 = (float)vb[base + 256];
            rv2 = (float)rb[base + 256];
        }
        // LN reduce across the block's 256 channels
        float s = y, sq = y * y;
#pragma unroll
        for (int o = 32; o > 0; o >>= 1) {
            s  += __shfl_xor(s, o);
            sq += __shfl_xor(sq, o);
        }
        if (lane == 0) { part[i & 1][0][wv] = s; part[i & 1][1][wv] = sq; }
        asm volatile("s_waitcnt lgkmcnt(0)" ::: "memory");
        __builtin_amdgcn_s_barrier();
        __builtin_amdgcn_sched_barrier(0);
        float S  = part[i & 1][0][0] + part[i & 1][0][1] + part[i & 1][0][2] + part[i & 1][0][3];
        float SQ = part[i & 1][1][0] + part[i & 1][1][1] + part[i & 1][1][2] + part[i & 1][1][3];
        float mu  = S * (1.0f / 256.0f);
        float var = SQ * (1.0f / 256.0f) - mu * mu;
        float rs  = rsqrtf(var + 1e-5f);
        float a   = (y - mu) * rs * gm + bt;
        abf[base] = (bf16_t)(a * rv);
        // state update
        float ww2 = wneg + pp;
        float p2  = fmaxf(ww2, kk);
        float e1b = __expf(ww2 - p2);
        float e2b = __expf(kk - p2);
        aa = e1b * aa + e2b * vv;
        bb = e1b * bb + e2b;
        pp = p2;
        kk = kk2; vv = vv2; rv = rv2;
        base += 256;
    }
}

// ---------------------------------------------------------------------------
extern "C" void kernel_launch(void* const* d_in, const int* in_sizes, int n_in,
                              void* d_out, int out_size, void* d_ws, size_t ws_size,
                              hipStream_t stream)
{
    const float* x     = (const float*)d_in[0];
    const float* c1w   = (const float*)d_in[1];
    const float* dw1   = (const float*)d_in[2];
    const float* dw2   = (const float*)d_in[3];
    const float* dw3   = (const float*)d_in[4];
    const float* p1w   = (const float*)d_in[5];
    const float* p2w   = (const float*)d_in[6];
    const float* p3w   = (const float*)d_in[7];
    const float* decay = (const float*)d_in[8];
    const float* first = (const float*)d_in[9];
    const float* mk    = (const float*)d_in[10];
    const float* mv    = (const float*)d_in[11];
    const float* mr    = (const float*)d_in[12];
    const float* kw    = (const float*)d_in[13];
    const float* vw    = (const float*)d_in[14];
    const float* rw    = (const float*)d_in[15];
    const float* ow    = (const float*)d_in[16];
    const float* gamma = (const float*)d_in[17];
    const float* beta  = (const float*)d_in[18];

    const size_t MBy = 1ull << 20;
    if (ws_size < 200 * MBy) return;

    char* ws = (char*)d_ws;
    // region plan (MiB):
    //   [0,64)    xcat[x|xx] bf16
    //   [64,160)  dcat bf16 (dw -> proj)    -> later k/v/r [M][256] each 32MiB
    //   [160,192) mid bf16 (conv1 -> dw)    -> later abf bf16
    //   [192,198) scan states (A1,B1,P1,A2,B2,P2) 1 MiB each
    //   [198,..)  weights bf16 (~1.4MiB); dwtb @199M+512K
    bf16_t* xcat = (bf16_t*)ws;
    bf16_t* dcat = (bf16_t*)(ws + 64 * MBy);
    bf16_t* kbuf = (bf16_t*)(ws + 64 * MBy);
    bf16_t* vbuf = (bf16_t*)(ws + 96 * MBy);
    bf16_t* rbuf = (bf16_t*)(ws + 128 * MBy);
    bf16_t* mid  = (bf16_t*)(ws + 160 * MBy);
    bf16_t* abf  = mid;
    float*  A1   = (float*)(ws + 192 * MBy);
    float*  B1   = (float*)(ws + 193 * MBy);
    float*  P1   = (float*)(ws + 194 * MBy);
    float*  A2   = (float*)(ws + 195 * MBy);
    float*  B2   = (float*)(ws + 196 * MBy);
    float*  P2   = (float*)(ws + 197 * MBy);
    bf16_t* wbf  = (bf16_t*)(ws + 198 * MBy);
    bf16_t* dwtb = (bf16_t*)(ws + 199 * MBy + 512 * 1024);
    bf16_t* wc1   = wbf;
    bf16_t* wproj = wbf + 65536;
    bf16_t* wkvrW = wbf + 262144;
    bf16_t* wout  = wbf + 655360;

    // cast x + all weight prep in one dispatch
    prep_all<<<11035, 256, 0, stream>>>(x, xcat, c1w, p1w, p2w, p3w,
                                        kw, vw, rw, ow, mk, mv, mr,
                                        dw1, dw2, dw3, wbf, dwtb);

    // mid = x @ conv1^T  (short K -> TM=256)
    gemm_bt<0, 256><<<dim3(2, Mrows / 256), 512, 0, stream>>>(
        xcat, 512, wc1, 256, mid, nullptr, nullptr, nullptr, 256, nullptr, 0);
    // depthwise (3 dilations) -> dcat
    dw_kernel<<<Mrows / 32, 256, 0, stream>>>(mid, dwtb, dcat);
    // s = dcat @ projcat^T ; xx = x + s  (K=768 -> TM=128; N=256 -> nbx=2!)
    gemm_bt<1, 128><<<dim3(2, Mrows / 128), 256, 0, stream>>>(
        dcat, 768, wproj, 768, xcat + 256, nullptr, nullptr, nullptr, 512, xcat, 512);
    // [k|v|sr] = [x|xx] @ kvrcat^T  (N=768 -> nbx=6; split stores, sigmoid)
    gemm_bt<2, 128><<<dim3(6, Mrows / 128), 256, 0, stream>>>(
        xcat, 512, wkvrW, 512, kbuf, vbuf, rbuf, nullptr, 256, nullptr, 0);
    // WKV scan
    wkv_pass1<<<dim3(NC, Bn), 256, 0, stream>>>(kbuf, vbuf, decay, A1, B1, P1);
    wkv_pass2<<<16, 64, 0, stream>>>(decay, A1, B1, P1, A2, B2, P2);
    // pass3 + LayerNorm + gate fused
    wkv_pass3<<<dim3(NC, Bn), 256, 0, stream>>>(kbuf, vbuf, rbuf, decay, first,
                                                A2, B2, P2, gamma, beta, abf);
    // out = a @ out_w^T  (short K -> TM=256, f32)
    gemm_bt<3, 256><<<dim3(2, Mrows / 256), 512, 0, stream>>>(
        abf, 256, wout, 256, nullptr, nullptr, nullptr, (float*)d_out, 256, nullptr, 0);
}

// Round 20
// 284.864 us; speedup vs baseline: 1.0164x; 1.0164x over previous
//
#include <hip/hip_runtime.h>
#include <hip/hip_bf16.h>

typedef __bf16 bf16_t;
typedef __attribute__((ext_vector_type(8))) __bf16 bf16x8;
typedef __attribute__((ext_vector_type(4))) __bf16 bf16x4;
typedef __attribute__((ext_vector_type(4))) float f32x4;

#define GLD16(gp, lp) __builtin_amdgcn_global_load_lds( \
    (__attribute__((address_space(1))) void*)(gp), \
    (__attribute__((address_space(3))) void*)(lp), 16, 0, 0)

static constexpr int Bn = 4, Hc = 128, Wc = 128, Cc = 256;
static constexpr int Tt = Hc * Wc;          // 16384
static constexpr int Mrows = Bn * Tt;       // 65536
static constexpr int NC = 256, CL = 64;     // wkv chunks: 256 chunks of 64
                                            // [R14 lesson: CL=32 cost +18us]
// [R17/R18 lesson: proj@TM=128 failure was a GRID bug (copied kvr's nbx=6 for
//  an N=256 output -> OOB epilogue writes). R19 isolated: proj@128+correct
//  grid = 289.5us vs proj@256 = 286.0us -> TM=256 is proj's optimum.]

// bijective XCD-aware swizzle (m204): contiguous work chunk per XCD
__device__ inline int xcd_swizzle(int orig, int nb)
{
    int q = nb >> 3, r = nb & 7;
    int xcd = orig & 7, slot = orig >> 3;
    return (xcd < r ? xcd * (q + 1) : r * (q + 1) + (xcd - r) * q) + slot;
}

// --- prep: cast x -> xcat; fold mixes, concat, cast weights; dw transpose ---
// blocks [0,8192): cast x;  [8192,11008): weight prep;  [11008,11035): dw^T
__global__ void prep_all(const float* __restrict__ x, bf16_t* __restrict__ xcat,
                         const float* __restrict__ c1,
                         const float* __restrict__ p1, const float* __restrict__ p2,
                         const float* __restrict__ p3,
                         const float* __restrict__ kw, const float* __restrict__ vw,
                         const float* __restrict__ rw, const float* __restrict__ ow,
                         const float* __restrict__ mk, const float* __restrict__ mv,
                         const float* __restrict__ mr,
                         const float* __restrict__ w1, const float* __restrict__ w2,
                         const float* __restrict__ w3,
                         bf16_t* __restrict__ wbf, bf16_t* __restrict__ dwtb)
{
    int bx = blockIdx.x;
    if (bx < 8192) {                          // cast x (8 f32/thread)
        int i = bx * 256 + threadIdx.x;
        int p = i >> 5;
        int cc = (i & 31) * 8;
        const float4* s = (const float4*)(x + (size_t)p * 256 + cc);
        float4 a = s[0], b = s[1];
        bf16x8 o;
        o[0] = (bf16_t)a.x; o[1] = (bf16_t)a.y; o[2] = (bf16_t)a.z; o[3] = (bf16_t)a.w;
        o[4] = (bf16_t)b.x; o[5] = (bf16_t)b.y; o[6] = (bf16_t)b.z; o[7] = (bf16_t)b.w;
        *(bf16x8*)(xcat + (size_t)p * 512 + cc) = o;
        return;
    }
    bx -= 8192;
    if (bx >= 2816) {                         // dw weight transpose tail (bf16)
        int tap = bx - 2816;                  // 0..26
        int c   = threadIdx.x;
        const float* src = (tap < 9) ? w1 : (tap < 18) ? w2 : w3;
        dwtb[tap * 256 + c] = (bf16_t)src[c * 9 + (tap % 9)];
        return;
    }
    int i = bx * 256 + threadIdx.x;           // 0 .. 720895
    float v;
    if (i < 65536) {                          // conv1 [256][256]
        v = c1[i];
    } else if (i < 262144) {                  // projcat [256][768]
        int j = i - 65536;
        int n = j / 768, k = j % 768;
        int br = k >> 8, c = k & 255;
        const float* pw = (br == 0) ? p1 : (br == 1) ? p2 : p3;
        v = pw[n * 256 + c];
    } else if (i < 655360) {                  // kvrcat [768][512], mix folded
        int j = i - 262144;
        int n = j / 512, k = j % 512;
        const float* W; const float* mix;
        if (n < 256)      { W = kw; mix = mk; }
        else if (n < 512) { W = vw; mix = mv; }
        else              { W = rw; mix = mr; }
        int nn = n & 255, c = k & 255;
        float m = mix[c];
        float f = (k < 256) ? m : (1.0f - m);
        v = W[nn * 256 + c] * f;
    } else {                                  // out_w [256][256]
        v = ow[i - 655360];
    }
    wbf[i] = (bf16_t)v;
}

// ---------------- bf16 MFMA GEMM, C = A @ Bw^T  (Bw is [N][K]) --------------
// Tile-M templated, per-GEMM selection (measured):
//   TM=128: 4 waves, 32 KiB LDS, 4 blocks/CU -> best for kvr (K=512: 71us)
//   TM=256: 8 waves, 48 KiB LDS, 3 blocks/CU -> best for conv1/proj/out
// Per K-tile: STAGE -> sync -> ds_read frags + 32 MFMA/wave -> sync; barrier
// drain hidden by co-resident blocks (m114 overlap).
// T2 swizzle: LDS block b of row r holds global block b^(r&7); GLD16 keeps a
// linear LDS dest, the global SOURCE is inverse-permuted, ds_read XORs back.
// EPI 0: store bf16                EPI 1: store bf16(aux + acc)  (xx = x + s)
// EPI 2: split store k/v/r (block-uniform), sigmoid on r      EPI 3: store f32
template<int EPI, int TM>
__global__ __launch_bounds__(TM * 2, 4)
void gemm_bt(const bf16_t* __restrict__ A, int lda,
             const bf16_t* __restrict__ Bw, int K,
             bf16_t* __restrict__ Cb, bf16_t* __restrict__ Cb2,
             bf16_t* __restrict__ Cb3,
             float* __restrict__ Cf, int ldc,
             const bf16_t* __restrict__ aux, int aux_ld)
{
    constexpr int RA = TM / 4;           // rows per staged chunk
    constexpr int CB = 512 / TM;         // B chunks (128 rows total)
    __shared__ bf16_t sA[TM * 64];
    __shared__ bf16_t sB[128 * 64];
    const int tid  = threadIdx.x;
    const int wid  = tid >> 6, lane = tid & 63;
    const int nbx  = gridDim.x;
    int work = xcd_swizzle(blockIdx.y * nbx + blockIdx.x, nbx * gridDim.y);
    const int bcol = (work % nbx) * 128;
    const int brow = (work / nbx) * TM;
    const int wm = (wid >> 1) * 64, wn = (wid & 1) * 64;   // wave tile 64x64
    const int lr = lane & 15, lq = lane >> 4;
    const int r0 = tid >> 3;             // staging row within chunk
    const int l7 = tid & 7;              // staging 16B-block within row
    const int sblk = l7 ^ (r0 & 7);      // inverse-swizzled source block

    f32x4 acc[4][4] = {};

    // stage one K-tile: A TM x 64 (4 chunks), B 128 x 64 (CB chunks);
    // linear LDS dest (wave-uniform base + lane*16), pre-swizzled source.
    auto STAGE = [&](int k0) {
#pragma unroll
        for (int c = 0; c < 4; c++)
            GLD16(A + (size_t)(brow + c * RA + r0) * lda + k0 + sblk * 8,
                  &sA[(c * RA + wid * 8) * 64]);
#pragma unroll
        for (int c = 0; c < CB; c++)
            GLD16(Bw + (size_t)(bcol + c * RA + r0) * K + k0 + sblk * 8,
                  &sB[(c * RA + wid * 8) * 64]);
    };

    const int knt = K >> 6;
    for (int t = 0; t < knt; ++t) {
        STAGE(t * 64);
        __syncthreads();                 // drain stage; other blocks hide it
        bf16x8 af[2][4], bg[2][4];
#pragma unroll
        for (int kk = 0; kk < 2; kk++) {
#pragma unroll
            for (int m = 0; m < 4; m++) {
                int rr = wm + m * 16 + lr;
                af[kk][m] = *(const bf16x8*)&sA
                    [rr * 64 + (((kk << 2) | lq) ^ (rr & 7)) * 8];
            }
#pragma unroll
            for (int n = 0; n < 4; n++) {
                int rr = wn + n * 16 + lr;
                bg[kk][n] = *(const bf16x8*)&sB
                    [rr * 64 + (((kk << 2) | lq) ^ (rr & 7)) * 8];
            }
        }
#pragma unroll
        for (int kk = 0; kk < 2; kk++)
#pragma unroll
            for (int m = 0; m < 4; m++)
#pragma unroll
                for (int n = 0; n < 4; n++)
                    acc[m][n] = __builtin_amdgcn_mfma_f32_16x16x32_bf16(
                        af[kk][m], bg[kk][n], acc[m][n], 0, 0, 0);
        __syncthreads();                 // all reads done before next STAGE
    }

    // epilogue: C/D layout col = lane&15, row = (lane>>4)*4 + j
#pragma unroll
    for (int m = 0; m < 4; m++) {
#pragma unroll
        for (int n = 0; n < 4; n++) {
            int col  = bcol + wn + n * 16 + lr;
            int row0 = brow + wm + m * 16 + lq * 4;
#pragma unroll
            for (int j = 0; j < 4; j++) {
                int row = row0 + j;
                float v = acc[m][n][j];
                if constexpr (EPI == 0) {
                    Cb[(size_t)row * ldc + col] = (bf16_t)v;
                } else if constexpr (EPI == 1) {
                    float xv = (float)aux[(size_t)row * aux_ld + col];
                    Cb[(size_t)row * ldc + col] = (bf16_t)(xv + v);
                } else if constexpr (EPI == 2) {
                    int cb = bcol >> 8;                // block-uniform: 0,1,2
                    bf16_t* dst = (cb == 0) ? Cb : (cb == 1) ? Cb2 : Cb3;
                    if (cb == 2) v = 1.0f / (1.0f + __expf(-v));
                    dst[(size_t)row * 256 + (col & 255)] = (bf16_t)v;
                } else {
                    Cf[(size_t)row * ldc + col] = v;
                }
            }
        }
    }
}

// ---------------- depthwise 3x3, dilations 1/2/3 -> dcat [M][768] -----------
// 4-pixel horizontal strip per thread, 8 channels. For 4 adjacent pixels the
// tap columns per (d,kh) form ONE contiguous span w-d..w+3+d (6/8/10 cols):
// load the span once, index statically sp[p + kw2*d] (fully unrolled).
template<int D>
__device__ inline void dw_dil(const bf16_t* __restrict__ mid, size_t img,
                              int h, int w, int c0, const bf16_t* swt,
                              bf16_t* __restrict__ dcat, size_t p0)
{
    constexpr int S = 4 + 2 * D;
    float acc[4][8] = {};
    const bf16x8 z = {};
#pragma unroll
    for (int kh = 0; kh < 3; kh++) {
        int hh = h + (kh - 1) * D;
        bool okh = (unsigned)hh < 128u;
        int hc = min(max(hh, 0), 127);
        const bf16_t* rowp = mid + (img + (size_t)(hc * 128)) * 256 + c0;
        bf16x8 sp[S];
#pragma unroll
        for (int s = 0; s < S; s++) {
            int ww = w - D + s;
            bool ok = okh && ((unsigned)ww < 128u);
            int wc = min(max(ww, 0), 127);
            bf16x8 m = *(const bf16x8*)(rowp + (size_t)wc * 256);
            sp[s] = ok ? m : z;
        }
#pragma unroll
        for (int kw2 = 0; kw2 < 3; kw2++) {
            bf16x8 wv = *(const bf16x8*)&swt[((D - 1) * 9 + kh * 3 + kw2) * 256 + c0];
#pragma unroll
            for (int p = 0; p < 4; p++) {
                bf16x8 m = sp[p + kw2 * D];
#pragma unroll
                for (int j = 0; j < 8; j++)
                    acc[p][j] += (float)m[j] * (float)wv[j];
            }
        }
    }
#pragma unroll
    for (int p = 0; p < 4; p++) {
        bf16x8 o;
#pragma unroll
        for (int j = 0; j < 8; j++) o[j] = (bf16_t)acc[p][j];
        *(bf16x8*)(dcat + (size_t)(p0 + p) * 768 + (D - 1) * 256 + c0) = o;
    }
}

__global__ __launch_bounds__(256)
void dw_kernel(const bf16_t* __restrict__ mid,
               const bf16_t* __restrict__ dwtb,
               bf16_t* __restrict__ dcat)
{
    __shared__ bf16_t swt[27 * 256];
    for (int i = threadIdx.x * 8; i < 27 * 256; i += 256 * 8)
        *(bf16x8*)&swt[i] = *(const bf16x8*)(dwtb + i);
    __syncthreads();

    int blk = xcd_swizzle(blockIdx.x, gridDim.x);   // L2-local halo reuse
    size_t p0 = (size_t)blk * 32 + (threadIdx.x >> 5) * 4;  // 4-px strip
    int c0 = (threadIdx.x & 31) * 8;                // channel group
    int t  = (int)(p0 & 16383);
    int h  = t >> 7, w = t & 127;
    size_t img = (p0 >> 14) << 14;                  // image base (pixels)

    dw_dil<1>(mid, img, h, w, c0, swt, dcat, p0);
    dw_dil<2>(mid, img, h, w, c0, swt, dcat, p0);
    dw_dil<3>(mid, img, h, w, c0, swt, dcat, p0);
}

// ---------------- WKV chunked scan (CL=64, NC=256) --------------------------
// pass1: per-chunk local (a,b,p) summary from zero state (prefetch next step)
__global__ void wkv_pass1(const bf16_t* __restrict__ kb, const bf16_t* __restrict__ vb,
                          const float* __restrict__ decay,
                          float* __restrict__ A1, float* __restrict__ B1,
                          float* __restrict__ P1)
{
    int c = threadIdx.x;
    int j = blockIdx.x;            // chunk
    int b = blockIdx.y;
    float wneg = -__expf(decay[c] * (1.0f / 16384.0f));
    float aa = 0.0f, bb = 0.0f, pp = -1e38f;
    size_t base = ((size_t)b * 16384 + (size_t)j * CL) * 256 + c;
    float kk = (float)kb[base];
    float vv = (float)vb[base];
    for (int i = 0; i < CL; i++) {
        float kk2 = 0.0f, vv2 = 0.0f;
        if (i + 1 < CL) {
            kk2 = (float)kb[base + 256];
            vv2 = (float)vb[base + 256];
        }
        float ww2 = wneg + pp;
        float p2  = fmaxf(ww2, kk);
        float e1  = __expf(ww2 - p2);
        float e2  = __expf(kk - p2);
        aa = e1 * aa + e2 * vv;
        bb = e1 * bb + e2;
        pp = p2;
        kk = kk2; vv = vv2;
        base += 256;
    }
    int idx = ((b * NC + j) * 256) + c;
    A1[idx] = aa; B1[idx] = bb; P1[idx] = pp;
}

// pass2: serial combine across chunks -> chunk-entry states.
// 16 blocks x 64 threads; unroll-4 with batched loads (latency / 4).
__global__ void wkv_pass2(const float* __restrict__ decay,
                          const float* __restrict__ A1, const float* __restrict__ B1,
                          const float* __restrict__ P1,
                          float* __restrict__ A2, float* __restrict__ B2,
                          float* __restrict__ P2)
{
    int c = (blockIdx.x & 3) * 64 + threadIdx.x;   // channel 0..255
    int b = blockIdx.x >> 2;                        // batch
    float wneg = -__expf(decay[c] * (1.0f / 16384.0f));
    float Lw = (float)CL * wneg;
    float aa = 0.0f, bb = 0.0f, pp = -1e38f;
    for (int j = 0; j < NC; j += 4) {
        float a4[4], b4[4], p4[4];
#pragma unroll
        for (int u = 0; u < 4; u++) {
            int idx = ((b * NC + j + u) * 256) + c;
            a4[u] = A1[idx]; b4[u] = B1[idx]; p4[u] = P1[idx];
        }
#pragma unroll
        for (int u = 0; u < 4; u++) {
            int idx = ((b * NC + j + u) * 256) + c;
            A2[idx] = aa; B2[idx] = bb; P2[idx] = pp;
            float q  = pp + Lw;
            float pn = fmaxf(q, p4[u]);
            float e1 = __expf(q - pn);
            float e2 = __expf(p4[u] - pn);
            aa = e1 * aa + e2 * a4[u];
            bb = e1 * bb + e2 * b4[u];
            pp = pn;
        }
    }
}

// pass3: re-run chunk with correct entry state + fused LayerNorm + gate ------
// Light barrier: lgkmcnt(0) (orders lane-0's part[] ds_write) + raw s_barrier
// -- NOT __syncthreads, whose vmcnt(0) drain would kill the k/v/r prefetch.
__global__ __launch_bounds__(256)
void wkv_pass3(const bf16_t* __restrict__ kb, const bf16_t* __restrict__ vb,
               const bf16_t* __restrict__ rb,
               const float* __restrict__ decay, const float* __restrict__ first,
               const float* __restrict__ A2, const float* __restrict__ B2,
               const float* __restrict__ P2,
               const float* __restrict__ gamma, const float* __restrict__ beta,
               bf16_t* __restrict__ abf)
{
    __shared__ float part[2][2][4];    // [step&1][s|sq][wave]
    int c = threadIdx.x;
    int j = blockIdx.x;
    int b = blockIdx.y;
    int wv = c >> 6, lane = c & 63;
    float wneg = -__expf(decay[c] * (1.0f / 16384.0f));
    float u  = first[c] * (1.0f / 16384.0f);
    float gm = gamma[c], bt = beta[c];
    int idx = ((b * NC + j) * 256) + c;
    float aa = A2[idx], bb = B2[idx], pp = P2[idx];
    size_t base = ((size_t)b * 16384 + (size_t)j * CL) * 256 + c;

    float kk = (float)kb[base];
    float vv = (float)vb[base];
    float rv = (float)rb[base];
    for (int i = 0; i < CL; i++) {
        float ww = u + kk;
        float p  = fmaxf(pp, ww);
        float e1 = __expf(pp - p);
        float e2 = __expf(ww - p);
        float y  = (e1 * aa + e2 * vv) / (e1 * bb + e2);
        // prefetch next step; stays in flight across the light barrier
        float kk2 = 0.0f, vv2 = 0.0f, rv2 = 0.0f;
        if (i + 1 < CL) {
            kk2 = (float)kb[base + 256];
            vv2 = (float)vb[base + 256];
            rv2 = (float)rb[base + 256];
        }
        // LN reduce across the block's 256 channels
        float s = y, sq = y * y;
#pragma unroll
        for (int o = 32; o > 0; o >>= 1) {
            s  += __shfl_xor(s, o);
            sq += __shfl_xor(sq, o);
        }
        if (lane == 0) { part[i & 1][0][wv] = s; part[i & 1][1][wv] = sq; }
        asm volatile("s_waitcnt lgkmcnt(0)" ::: "memory");
        __builtin_amdgcn_s_barrier();
        __builtin_amdgcn_sched_barrier(0);
        float S  = part[i & 1][0][0] + part[i & 1][0][1] + part[i & 1][0][2] + part[i & 1][0][3];
        float SQ = part[i & 1][1][0] + part[i & 1][1][1] + part[i & 1][1][2] + part[i & 1][1][3];
        float mu  = S * (1.0f / 256.0f);
        float var = SQ * (1.0f / 256.0f) - mu * mu;
        float rs  = rsqrtf(var + 1e-5f);
        float a   = (y - mu) * rs * gm + bt;
        abf[base] = (bf16_t)(a * rv);
        // state update
        float ww2 = wneg + pp;
        float p2  = fmaxf(ww2, kk);
        float e1b = __expf(ww2 - p2);
        float e2b = __expf(kk - p2);
        aa = e1b * aa + e2b * vv;
        bb = e1b * bb + e2b;
        pp = p2;
        kk = kk2; vv = vv2; rv = rv2;
        base += 256;
    }
}

// ---------------------------------------------------------------------------
extern "C" void kernel_launch(void* const* d_in, const int* in_sizes, int n_in,
                              void* d_out, int out_size, void* d_ws, size_t ws_size,
                              hipStream_t stream)
{
    const float* x     = (const float*)d_in[0];
    const float* c1w   = (const float*)d_in[1];
    const float* dw1   = (const float*)d_in[2];
    const float* dw2   = (const float*)d_in[3];
    const float* dw3   = (const float*)d_in[4];
    const float* p1w   = (const float*)d_in[5];
    const float* p2w   = (const float*)d_in[6];
    const float* p3w   = (const float*)d_in[7];
    const float* decay = (const float*)d_in[8];
    const float* first = (const float*)d_in[9];
    const float* mk    = (const float*)d_in[10];
    const float* mv    = (const float*)d_in[11];
    const float* mr    = (const float*)d_in[12];
    const float* kw    = (const float*)d_in[13];
    const float* vw    = (const float*)d_in[14];
    const float* rw    = (const float*)d_in[15];
    const float* ow    = (const float*)d_in[16];
    const float* gamma = (const float*)d_in[17];
    const float* beta  = (const float*)d_in[18];

    const size_t MBy = 1ull << 20;
    if (ws_size < 200 * MBy) return;

    char* ws = (char*)d_ws;
    // region plan (MiB):
    //   [0,64)    xcat[x|xx] bf16
    //   [64,160)  dcat bf16 (dw -> proj)    -> later k/v/r [M][256] each 32MiB
    //   [160,192) mid bf16 (conv1 -> dw)    -> later abf bf16
    //   [192,198) scan states (A1,B1,P1,A2,B2,P2) 1 MiB each
    //   [198,..)  weights bf16 (~1.4MiB); dwtb @199M+512K
    bf16_t* xcat = (bf16_t*)ws;
    bf16_t* dcat = (bf16_t*)(ws + 64 * MBy);
    bf16_t* kbuf = (bf16_t*)(ws + 64 * MBy);
    bf16_t* vbuf = (bf16_t*)(ws + 96 * MBy);
    bf16_t* rbuf = (bf16_t*)(ws + 128 * MBy);
    bf16_t* mid  = (bf16_t*)(ws + 160 * MBy);
    bf16_t* abf  = mid;
    float*  A1   = (float*)(ws + 192 * MBy);
    float*  B1   = (float*)(ws + 193 * MBy);
    float*  P1   = (float*)(ws + 194 * MBy);
    float*  A2   = (float*)(ws + 195 * MBy);
    float*  B2   = (float*)(ws + 196 * MBy);
    float*  P2   = (float*)(ws + 197 * MBy);
    bf16_t* wbf  = (bf16_t*)(ws + 198 * MBy);
    bf16_t* dwtb = (bf16_t*)(ws + 199 * MBy + 512 * 1024);
    bf16_t* wc1   = wbf;
    bf16_t* wproj = wbf + 65536;
    bf16_t* wkvrW = wbf + 262144;
    bf16_t* wout  = wbf + 655360;

    // cast x + all weight prep in one dispatch
    prep_all<<<11035, 256, 0, stream>>>(x, xcat, c1w, p1w, p2w, p3w,
                                        kw, vw, rw, ow, mk, mv, mr,
                                        dw1, dw2, dw3, wbf, dwtb);

    // mid = x @ conv1^T  (TM=256)
    gemm_bt<0, 256><<<dim3(2, Mrows / 256), 512, 0, stream>>>(
        xcat, 512, wc1, 256, mid, nullptr, nullptr, nullptr, 256, nullptr, 0);
    // depthwise (3 dilations) -> dcat
    dw_kernel<<<Mrows / 32, 256, 0, stream>>>(mid, dwtb, dcat);
    // s = dcat @ projcat^T ; xx = x + s  (TM=256, N=256 -> nbx=2)
    gemm_bt<1, 256><<<dim3(2, Mrows / 256), 512, 0, stream>>>(
        dcat, 768, wproj, 768, xcat + 256, nullptr, nullptr, nullptr, 512, xcat, 512);
    // [k|v|sr] = [x|xx] @ kvrcat^T  (TM=128, N=768 -> nbx=6; split, sigmoid)
    gemm_bt<2, 128><<<dim3(6, Mrows / 128), 256, 0, stream>>>(
        xcat, 512, wkvrW, 512, kbuf, vbuf, rbuf, nullptr, 256, nullptr, 0);
    // WKV scan
    wkv_pass1<<<dim3(NC, Bn), 256, 0, stream>>>(kbuf, vbuf, decay, A1, B1, P1);
    wkv_pass2<<<16, 64, 0, stream>>>(decay, A1, B1, P1, A2, B2, P2);
    // pass3 + LayerNorm + gate fused
    wkv_pass3<<<dim3(NC, Bn), 256, 0, stream>>>(kbuf, vbuf, rbuf, decay, first,
                                                A2, B2, P2, gamma, beta, abf);
    // out = a @ out_w^T  (TM=256, f32)
    gemm_bt<3, 256><<<dim3(2, Mrows / 256), 512, 0, stream>>>(
        abf, 256, wout, 256, nullptr, nullptr, nullptr, (float*)d_out, 256, nullptr, 0);
}